// Round 11
// baseline (669.442 us; speedup 1.0000x reference)
//
#include <hip/hip_runtime.h>
#include <math.h>

#define H 6
#define DH 64
#define D 384
#define L 16
#define WSZ ((size_t)(D) * (D))
#define RSZ ((size_t)(H) * (DH) * (DH))

typedef __attribute__((ext_vector_type(8))) short short8;
typedef __attribute__((ext_vector_type(4))) float f32x4;
typedef unsigned int uint_;

__device__ __forceinline__ float bf2f(unsigned short u) {
  union { unsigned int i; float f; } x; x.i = ((unsigned int)u) << 16; return x.f;
}
__device__ __forceinline__ unsigned short f2bf(float f) {
  unsigned int x = __float_as_uint(f);
  x = x + 0x7fffu + ((x >> 16) & 1u);
  return (unsigned short)(x >> 16);
}
__device__ __forceinline__ float blo(unsigned int u) { return __uint_as_float(u << 16); }
__device__ __forceinline__ float bhi(unsigned int u) { return __uint_as_float(u & 0xffff0000u); }
__device__ __forceinline__ float geluf(float x) {
  return 0.5f * x * (1.0f + erff(x * 0.70710678118654752f));
}

__global__ void zero_int_kernel(int* p, long n) {
  long i = (long)blockIdx.x * blockDim.x + threadIdx.x;
  long stride = (long)gridDim.x * blockDim.x;
  for (; i < n; i += stride) p[i] = 0;
}

// ---- fused pool+count+prep launch, 512 threads/block ----
// blocks [0, NPOOL): masked mean pool + L2 norm -> bf16, plus embedded degree count.
// blocks [NPOOL, NPOOL+2016): weight prep, 14 slots x 144 tiles of [384 n][384 k] bf16.
//   column order per node-type stack: k | vm | tq  (tq folds p_rel[h]/8).
// blocks [NPOOL+2016, +7): fused bias vector [bM1 1152 | bC1 1152 | bM2 384 | bC2 768].
__global__ __launch_bounds__(512) void poolprep_kernel(
    const float* __restrict__ tokM, const int* __restrict__ idsM,
    unsigned short* __restrict__ outM, int NM,
    const float* __restrict__ tokC, const int* __restrict__ idsC,
    unsigned short* __restrict__ outC, int NPOOL,
    const int* __restrict__ dc0, const int* __restrict__ dc1,
    int* __restrict__ deg0, int* __restrict__ deg1, int E, int CH,
    const float* __restrict__ lin_W, const float* __restrict__ kW,
    const float* __restrict__ qW, const float* __restrict__ vW,
    const float* __restrict__ aW, const float* __restrict__ a_rel,
    const float* __restrict__ m_rel, const float* __restrict__ p_rel,
    const float* __restrict__ kb, const float* __restrict__ qb,
    const float* __restrict__ vb,
    unsigned short* __restrict__ wbuf, float* __restrict__ bbuf) {
  int t = threadIdx.x;
  if ((int)blockIdx.x < NPOOL) {
    // --- embedded degree count ---
    {
      int e = blockIdx.x * CH + t;
      if (t < CH && e < 2 * E) {
        if (e < E) atomicAdd(&deg0[dc0[e]], 1);
        else atomicAdd(&deg1[dc1[e - E]], 1);
      }
    }
    // --- pooling ---
    int n = blockIdx.x;
    const float* tok; const int* ids; unsigned short* out;
    if (n < NM) { tok = tokM; ids = idsM; out = outM; }
    else { n -= NM; tok = tokC; ids = idsC; out = outC; }
    int rg = t / 96, c4 = t % 96;
    const float4* tp = (const float4*)(tok + (size_t)n * L * D);
    const int* ip = ids + (size_t)n * L;
    int cnt = 0;
#pragma unroll
    for (int l = 0; l < L; ++l) cnt += (ip[l] > 0);
    float4 s = {0.f, 0.f, 0.f, 0.f};
    if (t < 384) {
#pragma unroll
      for (int li = 0; li < 4; ++li) {
        int l = rg + li * 4;
        if (ip[l] > 0) {
          float4 v = tp[l * 96 + c4];
          s.x += v.x; s.y += v.y; s.z += v.z; s.w += v.w;
        }
      }
    }
    __shared__ float4 part[4][96];
    if (t < 384) part[rg][c4] = s;
    __syncthreads();
    float4 m4 = {0.f, 0.f, 0.f, 0.f};
    float dot = 0.f;
    float inv_cnt = 1.0f / fmaxf((float)cnt, 1e-9f);
    if (t < 96) {
      float4 a = part[0][t], b = part[1][t], c = part[2][t], d2 = part[3][t];
      m4.x = (a.x + b.x + c.x + d2.x) * inv_cnt;
      m4.y = (a.y + b.y + c.y + d2.y) * inv_cnt;
      m4.z = (a.z + b.z + c.z + d2.z) * inv_cnt;
      m4.w = (a.w + b.w + c.w + d2.w) * inv_cnt;
      dot = m4.x * m4.x + m4.y * m4.y + m4.z * m4.z + m4.w * m4.w;
    }
#pragma unroll
    for (int o = 32; o; o >>= 1) dot += __shfl_down(dot, o);
    __shared__ float wpart[8];
    if ((t & 63) == 0) wpart[t >> 6] = dot;
    __syncthreads();
    float tot = 0.f;
#pragma unroll
    for (int i = 0; i < 8; ++i) tot += wpart[i];
    float inv = 1.0f / fmaxf(sqrtf(tot), 1e-12f);
    if (t < 96) {
      uint2 o;
      o.x = (uint_)f2bf(m4.x * inv) | ((uint_)f2bf(m4.y * inv) << 16);
      o.y = (uint_)f2bf(m4.z * inv) | ((uint_)f2bf(m4.w * inv) << 16);
      ((uint2*)(out + (size_t)n * D))[t] = o;
    }
    return;
  }
  int q = blockIdx.x - NPOOL;
  if (q >= 14 * 144) {
    // ---- bias blocks ----
    int i = (q - 14 * 144) * 512 + t;
    if (i >= 3456) return;
    int gemm, col;
    if (i < 1152) { gemm = 0; col = i; }
    else if (i < 2304) { gemm = 1; col = i - 1152; }
    else if (i < 2688) { gemm = 2; col = i - 2304; }
    else { gemm = 3; col = i - 2688; }
    int sec = col / D, j = col % D, h = j >> 6, rr = j & 63;
    float out = 0.f;
    if (gemm == 0) {  // M1: k | vm(m_rel[1]) | tq(a_rel[0], p0)
      if (sec == 0) out = kb[j];
      else if (sec == 1) {
        const float* Mm = m_rel + RSZ + (size_t)h * 4096;
        float s = 0.f; for (int d = 0; d < 64; ++d) s += vb[h * 64 + d] * Mm[d * 64 + rr]; out = s;
      } else {
        const float* R = a_rel + (size_t)h * 4096 + (size_t)rr * 64;
        float s = 0.f; for (int f = 0; f < 64; ++f) s += qb[h * 64 + f] * R[f];
        out = s * p_rel[h] * 0.125f;
      }
    } else if (gemm == 1) {  // C1: k | vm(m_rel[0]) | tq(a_rel[1], p1)
      if (sec == 0) out = kb[D + j];
      else if (sec == 1) {
        const float* Mm = m_rel + (size_t)h * 4096;
        float s = 0.f; for (int d = 0; d < 64; ++d) s += vb[D + h * 64 + d] * Mm[d * 64 + rr]; out = s;
      } else {
        const float* R = a_rel + RSZ + (size_t)h * 4096 + (size_t)rr * 64;
        float s = 0.f; for (int f = 0; f < 64; ++f) s += qb[D + h * 64 + f] * R[f];
        out = s * p_rel[H + h] * 0.125f;
      }
    } else if (gemm == 2) {  // M2: tq(a_rel[2], p2)
      const float* R = a_rel + 2 * RSZ + (size_t)h * 4096 + (size_t)rr * 64;
      float s = 0.f; for (int f = 0; f < 64; ++f) s += qb[2 * D + h * 64 + f] * R[f];
      out = s * p_rel[2 * H + h] * 0.125f;
    } else {  // C2: k | vm(m_rel[2])
      if (sec == 0) out = kb[3 * D + j];
      else {
        const float* Mm = m_rel + 2 * RSZ + (size_t)h * 4096;
        float s = 0.f; for (int d = 0; d < 64; ++d) s += vb[3 * D + h * 64 + d] * Mm[d * 64 + rr]; out = s;
      }
    }
    bbuf[i] = out;
    return;
  }
  // ---- weight slots ----
  int z = q / 144;
  int r = q % 144;
  int px = r % 12, py = r / 12;
  int tx = t & 31, ty16 = t >> 5;  // ty16 in [0,16)
  const float* src; const float* rel = nullptr; const float* prl = nullptr; int type = 0;
  switch (z) {
    case 0: src = lin_W; break;
    case 1: src = lin_W + WSZ; break;
    case 2: src = kW; break;                                              // k_M1
    case 3: type = 2; src = vW; rel = m_rel + RSZ; break;                 // vm_M1
    case 4: type = 1; src = qW; rel = a_rel; prl = p_rel; break;          // tq_M1
    case 5: src = kW + WSZ; break;                                        // k_C1
    case 6: type = 2; src = vW + WSZ; rel = m_rel; break;                 // vm_C1
    case 7: type = 1; src = qW + WSZ; rel = a_rel + RSZ; prl = p_rel + H; break;  // tq_C1
    case 8: type = 1; src = qW + 2 * WSZ; rel = a_rel + 2 * RSZ; prl = p_rel + 2 * H; break;  // tq_M2
    case 9: src = kW + 3 * WSZ; break;                                    // k_C2
    case 10: type = 2; src = vW + 3 * WSZ; rel = m_rel + 2 * RSZ; break;  // vm_C2
    case 11: src = aW; break;
    case 12: src = aW + WSZ; break;
    default: src = aW + 2 * WSZ; break;
  }
  unsigned short* dst = wbuf + (size_t)z * WSZ;
  int bx = px * 32;  // k range
  int by = py * 32;  // n range
  if (type == 0) {
    __shared__ float tile[32][33];
#pragma unroll
    for (int s = 0; s < 2; ++s) {
      int r2 = ty16 + s * 16;
      tile[r2][tx] = src[(size_t)(bx + r2) * D + by + tx];
    }
    __syncthreads();
#pragma unroll
    for (int s = 0; s < 2; ++s) {
      int ny = ty16 + s * 16;
      dst[(size_t)(by + ny) * D + bx + tx] = f2bf(tile[tx][ny]);
    }
  } else if (type == 1) {
    int h = by >> 6, d0 = by & 63;
    float sc = prl[h] * 0.125f;
    __shared__ float Wt_[32][65], Rt[32][65];
#pragma unroll
    for (int i = 0; i < 4; ++i) {
      int idx = t + i * 512;
      int wr = idx >> 6, wc = idx & 63;
      Wt_[wr][wc] = src[(size_t)(bx + wr) * D + h * 64 + wc];
      Rt[wr][wc] = rel[(size_t)h * 4096 + (size_t)(d0 + wr) * 64 + wc];
    }
    __syncthreads();
#pragma unroll
    for (int s = 0; s < 2; ++s) {
      int ny = ty16 + s * 16;
      float acc = 0.f;
#pragma unroll 16
      for (int f = 0; f < 64; ++f) acc += Wt_[tx][f] * Rt[ny][f];
      dst[(size_t)(by + ny) * D + bx + tx] = f2bf(acc * sc);
    }
  } else {
    int h = by >> 6, f0 = by & 63;
    __shared__ float Wt2[32][65];
    __shared__ float Mt[64][33];
#pragma unroll
    for (int i = 0; i < 4; ++i) {
      int idx = t + i * 512;
      int wr = idx >> 6, wc = idx & 63;
      Wt2[wr][wc] = src[(size_t)(bx + wr) * D + h * 64 + wc];
      int dr = idx >> 5, fc = idx & 31;
      Mt[dr][fc] = rel[(size_t)h * 4096 + (size_t)dr * 64 + f0 + fc];
    }
    __syncthreads();
#pragma unroll
    for (int s = 0; s < 2; ++s) {
      int ny = ty16 + s * 16;
      float acc = 0.f;
#pragma unroll 16
      for (int d = 0; d < 64; ++d) acc += Wt2[tx][d] * Mt[d][ny];
      dst[(size_t)(by + ny) * D + bx + tx] = f2bf(acc);
    }
  }
}

// wave-shuffle scan: 3 barriers per 1024-chunk
__global__ void scan2_kernel(const int* __restrict__ deg0, int* __restrict__ off0, int N0,
                             const int* __restrict__ deg1, int* __restrict__ off1, int N1) {
  const int* deg = blockIdx.x ? deg1 : deg0;
  int* off = blockIdx.x ? off1 : off0;
  int N = blockIdx.x ? N1 : N0;
  __shared__ int wsum[16];
  __shared__ int carrySh;
  int tid = threadIdx.x;
  int lane = tid & 63, wid = tid >> 6;
  if (tid == 0) carrySh = 0;
  __syncthreads();
  for (int base = 0; base < N; base += 1024) {
    int i = base + tid;
    int v = (i < N) ? deg[i] : 0;
    int s = v;
#pragma unroll
    for (int o = 1; o < 64; o <<= 1) {
      int t2 = __shfl_up(s, o);
      if (lane >= o) s += t2;
    }
    if (lane == 63) wsum[wid] = s;
    __syncthreads();
    int wpre = 0;
    for (int j = 0; j < wid; ++j) wpre += wsum[j];
    int c = carrySh;
    if (i < N) off[i] = c + wpre + s - v;
    __syncthreads();
    if (tid == 1023) carrySh = c + wpre + s;
    __syncthreads();
  }
  if (tid == 0) off[N] = carrySh;
}

// ---------------- fused per-dst attention, u32-vectorized, 2-edge unrolled ----------------
// proj layout k | vm | tq: per-edge gather of k+vm is one contiguous 1536-B region.
struct AttnP {
  const unsigned short* kb;
  const unsigned short* tqb;
  const unsigned short* vmb;
  const int* off;
  const int* elist;
  unsigned short* aggb;
  int N, sk, st, sv, nb;
};

__global__ void attn_kernel(AttnP a0, AttnP a1) {
  bool first = (int)blockIdx.x < a0.nb;
  AttnP a = first ? a0 : a1;
  int bx = first ? (int)blockIdx.x : (int)blockIdx.x - a0.nb;
  int node = bx * 4 + (threadIdx.x >> 6);
  int lane = threadIdx.x & 63;
  if (node >= a.N) return;
  int e0 = a.off[node], e1 = a.off[node + 1];
  const uint_* tq32 = (const uint_*)(a.tqb + (size_t)node * a.st);
  float tq0[3], tq1[3], m[3], den[3], ac0[3], ac1[3];
#pragma unroll
  for (int j = 0; j < 3; ++j) {
    uint_ u = tq32[lane + 64 * j];
    tq0[j] = blo(u); tq1[j] = bhi(u);
    m[j] = -1e30f; den[j] = 0.f; ac0[j] = 0.f; ac1[j] = 0.f;
  }
  int i = e0;
  for (; i + 2 <= e1; i += 2) {
    int s0 = a.elist[i], s1 = a.elist[i + 1];
    const uint_* k0 = (const uint_*)(a.kb + (size_t)s0 * a.sk);
    const uint_* k1 = (const uint_*)(a.kb + (size_t)s1 * a.sk);
    const uint_* v0 = (const uint_*)(a.vmb + (size_t)s0 * a.sv);
    const uint_* v1 = (const uint_*)(a.vmb + (size_t)s1 * a.sv);
    float pa[3], pb[3]; uint_ va[3], vb[3];
#pragma unroll
    for (int j = 0; j < 3; ++j) {
      uint_ ka = k0[lane + 64 * j], kbu = k1[lane + 64 * j];
      va[j] = v0[lane + 64 * j]; vb[j] = v1[lane + 64 * j];
      pa[j] = blo(ka) * tq0[j] + bhi(ka) * tq1[j];
      pb[j] = blo(kbu) * tq0[j] + bhi(kbu) * tq1[j];
    }
#pragma unroll
    for (int o = 1; o <= 16; o <<= 1)
#pragma unroll
      for (int j = 0; j < 3; ++j) {
        pa[j] += __shfl_xor(pa[j], o);
        pb[j] += __shfl_xor(pb[j], o);
      }
#pragma unroll
    for (int j = 0; j < 3; ++j) {
      float mn = fmaxf(m[j], fmaxf(pa[j], pb[j]));
      float r = __expf(m[j] - mn);
      float p0 = __expf(pa[j] - mn);
      float p1 = __expf(pb[j] - mn);
      den[j] = den[j] * r + p0 + p1;
      ac0[j] = ac0[j] * r + p0 * blo(va[j]) + p1 * blo(vb[j]);
      ac1[j] = ac1[j] * r + p0 * bhi(va[j]) + p1 * bhi(vb[j]);
      m[j] = mn;
    }
  }
  if (i < e1) {
    int s0 = a.elist[i];
    const uint_* k0 = (const uint_*)(a.kb + (size_t)s0 * a.sk);
    const uint_* v0 = (const uint_*)(a.vmb + (size_t)s0 * a.sv);
    float pa[3]; uint_ va[3];
#pragma unroll
    for (int j = 0; j < 3; ++j) {
      uint_ ka = k0[lane + 64 * j];
      va[j] = v0[lane + 64 * j];
      pa[j] = blo(ka) * tq0[j] + bhi(ka) * tq1[j];
    }
#pragma unroll
    for (int o = 1; o <= 16; o <<= 1)
#pragma unroll
      for (int j = 0; j < 3; ++j) pa[j] += __shfl_xor(pa[j], o);
#pragma unroll
    for (int j = 0; j < 3; ++j) {
      float mn = fmaxf(m[j], pa[j]);
      float r = __expf(m[j] - mn);
      float p0 = __expf(pa[j] - mn);
      den[j] = den[j] * r + p0;
      ac0[j] = ac0[j] * r + p0 * blo(va[j]);
      ac1[j] = ac1[j] * r + p0 * bhi(va[j]);
      m[j] = mn;
    }
  }
  uint_* op32 = (uint_*)(a.aggb + (size_t)node * D);
#pragma unroll
  for (int j = 0; j < 3; ++j) {
    float o0 = (e1 > e0) ? ac0[j] / den[j] : 0.f;
    float o1 = (e1 > e0) ? ac1[j] / den[j] : 0.f;
    op32[lane + 64 * j] = (uint_)f2bf(geluf(o0)) | ((uint_)f2bf(geluf(o1)) << 16);
  }
}

// ---------------- MFMA bf16 GEMM, dual-problem, double-buffered; z==2 slice = scatter ----------------
struct GemmP {
  const unsigned short* A;
  const unsigned short* Wt;
  const float* bias;
  float* Cf;
  unsigned short* Cb;
  const unsigned short* xold;  // bf16 skip input
  const float* skipPtr;
  int M, N, cpitch, relu;
};
struct ScatP {
  const int *d0, *s0, *off0;
  int *cur0, *el0;
  const int *d1, *s1, *off1;
  int *cur1, *el1;
  int E;
};

__global__ __launch_bounds__(256) void gemm_bf16(GemmP q0, GemmP q1, ScatP sc) {
  if (blockIdx.z == 2) {
    int nb = gridDim.x * gridDim.y;
    int flat = blockIdx.y * gridDim.x + blockIdx.x;
    for (int e = flat * 256 + threadIdx.x; e < 2 * sc.E; e += nb * 256) {
      if (e < sc.E) {
        int d = sc.d0[e];
        sc.el0[sc.off0[d] + atomicAdd(&sc.cur0[d], 1)] = sc.s0[e];
      } else {
        int ee = e - sc.E;
        int d = sc.d1[ee];
        sc.el1[sc.off1[d] + atomicAdd(&sc.cur1[d], 1)] = sc.s1[ee];
      }
    }
    return;
  }
  GemmP p = blockIdx.z ? q1 : q0;
  const int bm = blockIdx.x * 128, bn = blockIdx.y * 128;
  if (bm >= p.M || bn >= p.N) return;
  __shared__ __align__(16) unsigned short As[2][128 * 64];
  __shared__ __align__(16) unsigned short Bs[2][128 * 64];
  const int tid = threadIdx.x;
  const int w = tid >> 6, lane = tid & 63;

  auto stage = [&](int t, int buf) {
#pragma unroll
    for (int i = 0; i < 4; ++i) {
      int cid = (w * 4 + i) * 64 + lane;
      int row = cid >> 3;
      int cg = (cid & 7) ^ (row & 7);
      int grow = bm + row;
      if (grow >= p.M) grow = p.M - 1;
      const unsigned short* gp = p.A + (size_t)grow * D + t * 64 + cg * 8;
      __builtin_amdgcn_global_load_lds((const __attribute__((address_space(1))) void*)gp,
                                       (__attribute__((address_space(3))) void*)&As[buf][(w * 4 + i) * 512],
                                       16, 0, 0);
    }
#pragma unroll
    for (int i = 0; i < 4; ++i) {
      int cid = (w * 4 + i) * 64 + lane;
      int row = cid >> 3;
      int cg = (cid & 7) ^ (row & 7);
      const unsigned short* gp = p.Wt + (size_t)(bn + row) * D + t * 64 + cg * 8;
      __builtin_amdgcn_global_load_lds((const __attribute__((address_space(1))) void*)gp,
                                       (__attribute__((address_space(3))) void*)&Bs[buf][(w * 4 + i) * 512],
                                       16, 0, 0);
    }
  };

  stage(0, 0);
  __syncthreads();

  const int wr = w >> 1, wc = w & 1;
  const int la = lane & 15, hi = lane >> 4;
  f32x4 acc[4][4] = {};

  for (int t = 0; t < 6; ++t) {
    if (t < 5) stage(t + 1, (t + 1) & 1);
    const unsigned short* Ab = As[t & 1];
    const unsigned short* Bb = Bs[t & 1];
#pragma unroll
    for (int ks = 0; ks < 2; ++ks) {
      int c = ks * 4 + hi;
      short8 af[4], bfr[4];
#pragma unroll
      for (int mi = 0; mi < 4; ++mi) {
        int row = wr * 64 + mi * 16 + la;
        af[mi] = *(const short8*)&Ab[row * 64 + ((c ^ (row & 7)) * 8)];
      }
#pragma unroll
      for (int n = 0; n < 4; ++n) {
        int col = wc * 64 + n * 16 + la;
        bfr[n] = *(const short8*)&Bb[col * 64 + ((c ^ (col & 7)) * 8)];
      }
#pragma unroll
      for (int mi = 0; mi < 4; ++mi)
#pragma unroll
        for (int n = 0; n < 4; ++n)
          acc[mi][n] = __builtin_amdgcn_mfma_f32_16x16x32_bf16(af[mi], bfr[n], acc[mi][n], 0, 0, 0);
    }
    __syncthreads();
  }

  float sa = 0.f;
  if (p.xold) sa = 1.0f / (1.0f + __expf(-*p.skipPtr));
#pragma unroll
  for (int mi = 0; mi < 4; ++mi) {
#pragma unroll
    for (int n = 0; n < 4; ++n) {
#pragma unroll
      for (int r = 0; r < 4; ++r) {
        int row = bm + wr * 64 + mi * 16 + hi * 4 + r;
        int col = bn + wc * 64 + n * 16 + la;
        if (row >= p.M) continue;
        float v = acc[mi][n][r] + p.bias[col];
        if (p.relu) v = fmaxf(v, 0.f);
        if (p.xold) v = sa * v + (1.0f - sa) * bf2f(p.xold[(size_t)row * D + col]);
        if (p.Cf) p.Cf[(size_t)row * p.cpitch + col] = v;
        if (p.Cb) p.Cb[(size_t)row * p.cpitch + col] = f2bf(v);
      }
    }
  }
}

extern "C" void kernel_launch(void* const* d_in, const int* in_sizes, int n_in,
                              void* d_out, int out_size, void* d_ws, size_t ws_size,
                              hipStream_t stream) {
  const float* tok_msg = (const float*)d_in[0];
  const float* tok_con = (const float*)d_in[1];
  const int* ids_msg = (const int*)d_in[2];
  const int* ids_con = (const int*)d_in[3];
  const int* src_cm = (const int*)d_in[4];
  const int* dst_cm = (const int*)d_in[5];
  const int* src_mc = (const int*)d_in[6];
  const int* dst_mc = (const int*)d_in[7];
  const float* lin_W = (const float*)d_in[8];
  const float* lin_b = (const float*)d_in[9];
  const float* kW = (const float*)d_in[10];
  const float* kb = (const float*)d_in[11];
  const float* qW = (const float*)d_in[12];
  const float* qb = (const float*)d_in[13];
  const float* vW = (const float*)d_in[14];
  const float* vb = (const float*)d_in[15];
  const float* aW = (const float*)d_in[16];
  const float* ab = (const float*)d_in[17];
  const float* a_rel = (const float*)d_in[18];
  const float* m_rel = (const float*)d_in[19];
  const float* p_rel = (const float*)d_in[20];
  const float* skip = (const float*)d_in[21];

  const int NM = in_sizes[2] / L;
  const int NC = in_sizes[3] / L;
  const int E = in_sizes[4];

  char* wsb = (char*)d_ws;
  size_t woff = 0;
  auto alloc = [&](size_t bytes) {
    woff = (woff + 255) & ~(size_t)255;
    void* p = wsb + woff;
    woff += bytes;
    return p;
  };
  const size_t NMe = (size_t)NM * D, NCe = (size_t)NC * D;
  unsigned short* poolM = (unsigned short*)alloc(NMe * 2);
  unsigned short* poolC = (unsigned short*)alloc(NCe * 2);
  unsigned short* x0b = (unsigned short*)alloc(NMe * 2);
  unsigned short* x1b = (unsigned short*)alloc(NCe * 2);
  unsigned short* xn0b = (unsigned short*)alloc(NMe * 2);
  unsigned short* xn1b = (unsigned short*)alloc(NCe * 2);
  unsigned short* projM1 = (unsigned short*)alloc((size_t)NM * 1152 * 2);
  unsigned short* projC1 = (unsigned short*)alloc((size_t)NC * 1152 * 2);
  unsigned short* projM2 = (unsigned short*)alloc((size_t)NM * 384 * 2);
  unsigned short* projC2 = (unsigned short*)alloc((size_t)NC * 768 * 2);
  unsigned short* aggM = (unsigned short*)alloc(NMe * 2);
  unsigned short* aggC = (unsigned short*)alloc(NCe * 2);
  unsigned short* wbuf = (unsigned short*)alloc(14 * WSZ * 2);
  float* bbuf = (float*)alloc(3456 * 4);
  // CSR ints: ONE contiguous block, hand-sliced (no per-array padding)
  long nz = 2L * NM + 2L * NC;  // deg0|cur0|deg1|cur1 prefix zeroed every launch
  int* ibase = (int*)alloc((size_t)(nz + NM + 1 + NC + 1 + 2L * E) * 4);
  int* deg0 = ibase;
  int* cur0 = deg0 + NM;
  int* deg1 = cur0 + NM;
  int* cur1 = deg1 + NC;
  int* off0 = cur1 + NC;
  int* off1 = off0 + NM + 1;
  int* el0 = off1 + NC + 1;
  int* el1 = el0 + E;

  dim3 b256(256);
  const int mbM = (NM + 127) / 128, mbC = (NC + 127) / 128;
  const int mbMax = (mbM > mbC) ? mbM : mbC;
  ScatP scNone = {};
  ScatP scAll = {dst_cm, src_cm, off0, cur0, el0, dst_mc, src_mc, off1, cur1, el1, E};

  // 1) zero deg/cur
  zero_int_kernel<<<64, b256, 0, stream>>>(ibase, nz);

  // 2) pool+count (HBM-bound) with weight/bias prep riding along as extra blocks
  const int NPOOL = NM + NC;
  const int CH = (2 * E + NPOOL - 1) / NPOOL;
  poolprep_kernel<<<NPOOL + 14 * 144 + 7, 512, 0, stream>>>(
      tok_msg, ids_msg, poolM, NM, tok_con, ids_con, poolC, NPOOL,
      dst_cm, dst_mc, deg0, deg1, E, CH,
      lin_W, kW, qW, vW, aW, a_rel, m_rel, p_rel, kb, qb, vb, wbuf, bbuf);

  // 3) scan (tiny)
  scan2_kernel<<<2, 1024, 0, stream>>>(deg0, off0, NM, deg1, off1, NC);

  // 4) initial linear (relu) || CSR scatter (z==2)
  {
    GemmP p0 = {poolM, wbuf, lin_b, nullptr, x0b, nullptr, nullptr, NM, D, D, 1};
    GemmP p1 = {poolC, wbuf + WSZ, lin_b + D, nullptr, x1b, nullptr, nullptr, NC, D, D, 1};
    gemm_bf16<<<dim3(mbMax, 3, 3), b256, 0, stream>>>(p0, p1, scAll);
  }
  // 5) layer 1: fused k|vm|tq projections, both node types
  {
    GemmP p0 = {x0b, wbuf + 2 * WSZ, bbuf, nullptr, projM1, nullptr, nullptr, NM, 1152, 1152, 0};
    GemmP p1 = {x1b, wbuf + 5 * WSZ, bbuf + 1152, nullptr, projC1, nullptr, nullptr, NC, 1152, 1152, 0};
    gemm_bf16<<<dim3(mbMax, 9, 2), b256, 0, stream>>>(p0, p1, scNone);
  }
  // 6) layer 1 attention, both edge types (k|vm adjacent -> contiguous gathers)
  {
    AttnP a0 = {projC1, projM1 + 768, projC1 + 384, off0, el0, aggM, NM, 1152, 1152, 1152, (NM + 3) / 4};
    AttnP a1 = {projM1, projC1 + 768, projM1 + 384, off1, el1, aggC, NC, 1152, 1152, 1152, (NC + 3) / 4};
    attn_kernel<<<(NM + 3) / 4 + (NC + 3) / 4, b256, 0, stream>>>(a0, a1);
  }
  // 7) layer 1 a-proj + skip blend (bf16 xold)
  {
    GemmP p0 = {aggM, wbuf + 11 * WSZ, ab, nullptr, xn0b, x0b, skip + 0, NM, D, D, 0};
    GemmP p1 = {aggC, wbuf + 12 * WSZ, ab + D, nullptr, xn1b, x1b, skip + 1, NC, D, D, 0};
    gemm_bf16<<<dim3(mbMax, 3, 2), b256, 0, stream>>>(p0, p1, scNone);
  }
  // 8) layer 2 projections (M: tq only, N=384; C: k|vm, N=768)
  {
    GemmP p0 = {xn0b, wbuf + 8 * WSZ, bbuf + 2304, nullptr, projM2, nullptr, nullptr, NM, 384, 384, 0};
    GemmP p1 = {xn1b, wbuf + 9 * WSZ, bbuf + 2688, nullptr, projC2, nullptr, nullptr, NC, 768, 768, 0};
    gemm_bf16<<<dim3(mbMax, 6, 2), b256, 0, stream>>>(p0, p1, scNone);
  }
  // 9) layer 2 attention (edge type 0 only)
  {
    AttnP a0 = {projC2, projM2, projC2 + 384, off0, el0, aggM, NM, 768, 384, 768, (NM + 3) / 4};
    AttnP a1 = a0;
    attn_kernel<<<(NM + 3) / 4, b256, 0, stream>>>(a0, a1);
  }
  // 10) layer 2 a-proj -> d_out (f32), bf16 xold
  {
    GemmP p0 = {aggM, wbuf + 13 * WSZ, ab + 2 * D, (float*)d_out, nullptr, xn0b, skip + 2, NM, D, D, 0};
    GemmP p1 = p0;
    gemm_bf16<<<dim3(mbM, 3, 1), b256, 0, stream>>>(p0, p1, scNone);
  }
}

// Round 12
// 628.248 us; speedup vs baseline: 1.0656x; 1.0656x over previous
//
#include <hip/hip_runtime.h>
#include <math.h>

#define H 6
#define DH 64
#define D 384
#define L 16
#define WSZ ((size_t)(D) * (D))
#define RSZ ((size_t)(H) * (DH) * (DH))

typedef __attribute__((ext_vector_type(8))) short short8;
typedef __attribute__((ext_vector_type(4))) float f32x4;
typedef unsigned int uint_;

__device__ __forceinline__ float bf2f(unsigned short u) {
  union { unsigned int i; float f; } x; x.i = ((unsigned int)u) << 16; return x.f;
}
__device__ __forceinline__ unsigned short f2bf(float f) {
  unsigned int x = __float_as_uint(f);
  x = x + 0x7fffu + ((x >> 16) & 1u);
  return (unsigned short)(x >> 16);
}
__device__ __forceinline__ float blo(unsigned int u) { return __uint_as_float(u << 16); }
__device__ __forceinline__ float bhi(unsigned int u) { return __uint_as_float(u & 0xffff0000u); }
__device__ __forceinline__ float geluf(float x) {
  return 0.5f * x * (1.0f + erff(x * 0.70710678118654752f));
}

__global__ void zero_int_kernel(int* p, long n) {
  long i = (long)blockIdx.x * blockDim.x + threadIdx.x;
  long stride = (long)gridDim.x * blockDim.x;
  for (; i < n; i += stride) p[i] = 0;
}

// ---- fused pool+count+prep launch, 512 threads/block, UNION LDS (16.8 KB not 43.5 KB) ----
// blocks [0, NPOOL): masked mean pool + L2 norm -> bf16, plus embedded degree count.
// blocks [NPOOL, NPOOL+2016): weight prep, 14 slots x 144 tiles of [384 n][384 k] bf16.
//   R10 column order per node-type stack: k | tq | vm  (tq folds p_rel[h]/8).
// blocks [NPOOL+2016, +7): fused bias vector [bM1 1152 | bC1 1152 | bM2 384 | bC2 768].
__global__ __launch_bounds__(512) void poolprep_kernel(
    const float* __restrict__ tokM, const int* __restrict__ idsM,
    unsigned short* __restrict__ outM, int NM,
    const float* __restrict__ tokC, const int* __restrict__ idsC,
    unsigned short* __restrict__ outC, int NPOOL,
    const int* __restrict__ dc0, const int* __restrict__ dc1,
    int* __restrict__ deg0, int* __restrict__ deg1, int E, int CH,
    const float* __restrict__ lin_W, const float* __restrict__ kW,
    const float* __restrict__ qW, const float* __restrict__ vW,
    const float* __restrict__ aW, const float* __restrict__ a_rel,
    const float* __restrict__ m_rel, const float* __restrict__ p_rel,
    const float* __restrict__ kb, const float* __restrict__ qb,
    const float* __restrict__ vb,
    unsigned short* __restrict__ wbuf, float* __restrict__ bbuf) {
  __shared__ __align__(16) char smem[16768];  // union across all branches
  int t = threadIdx.x;
  if ((int)blockIdx.x < NPOOL) {
    // --- embedded degree count ---
    {
      int e = blockIdx.x * CH + t;
      if (t < CH && e < 2 * E) {
        if (e < E) atomicAdd(&deg0[dc0[e]], 1);
        else atomicAdd(&deg1[dc1[e - E]], 1);
      }
    }
    // --- pooling ---
    float4 (*part)[96] = (float4(*)[96])smem;
    float* wpart = (float*)(smem + 6144);
    int n = blockIdx.x;
    const float* tok; const int* ids; unsigned short* out;
    if (n < NM) { tok = tokM; ids = idsM; out = outM; }
    else { n -= NM; tok = tokC; ids = idsC; out = outC; }
    int rg = t / 96, c4 = t % 96;
    const float4* tp = (const float4*)(tok + (size_t)n * L * D);
    const int* ip = ids + (size_t)n * L;
    int cnt = 0;
#pragma unroll
    for (int l = 0; l < L; ++l) cnt += (ip[l] > 0);
    float4 s = {0.f, 0.f, 0.f, 0.f};
    if (t < 384) {
#pragma unroll
      for (int li = 0; li < 4; ++li) {
        int l = rg + li * 4;
        if (ip[l] > 0) {
          float4 v = tp[l * 96 + c4];
          s.x += v.x; s.y += v.y; s.z += v.z; s.w += v.w;
        }
      }
      part[rg][c4] = s;
    }
    __syncthreads();
    float4 m4 = {0.f, 0.f, 0.f, 0.f};
    float dot = 0.f;
    float inv_cnt = 1.0f / fmaxf((float)cnt, 1e-9f);
    if (t < 96) {
      float4 a = part[0][t], b = part[1][t], c = part[2][t], d2 = part[3][t];
      m4.x = (a.x + b.x + c.x + d2.x) * inv_cnt;
      m4.y = (a.y + b.y + c.y + d2.y) * inv_cnt;
      m4.z = (a.z + b.z + c.z + d2.z) * inv_cnt;
      m4.w = (a.w + b.w + c.w + d2.w) * inv_cnt;
      dot = m4.x * m4.x + m4.y * m4.y + m4.z * m4.z + m4.w * m4.w;
    }
#pragma unroll
    for (int o = 32; o; o >>= 1) dot += __shfl_down(dot, o);
    if ((t & 63) == 0) wpart[t >> 6] = dot;
    __syncthreads();
    float tot = 0.f;
#pragma unroll
    for (int i = 0; i < 8; ++i) tot += wpart[i];
    float inv = 1.0f / fmaxf(sqrtf(tot), 1e-12f);
    if (t < 96) {
      uint2 o;
      o.x = (uint_)f2bf(m4.x * inv) | ((uint_)f2bf(m4.y * inv) << 16);
      o.y = (uint_)f2bf(m4.z * inv) | ((uint_)f2bf(m4.w * inv) << 16);
      ((uint2*)(out + (size_t)n * D))[t] = o;
    }
    return;
  }
  int q = blockIdx.x - NPOOL;
  if (q >= 14 * 144) {
    // ---- bias blocks (no LDS) ----
    int i = (q - 14 * 144) * 512 + t;
    if (i >= 3456) return;
    int gemm, col;
    if (i < 1152) { gemm = 0; col = i; }
    else if (i < 2304) { gemm = 1; col = i - 1152; }
    else if (i < 2688) { gemm = 2; col = i - 2304; }
    else { gemm = 3; col = i - 2688; }
    int sec = col / D, j = col % D, h = j >> 6, rr = j & 63;
    float out = 0.f;
    if (gemm == 0) {  // M1: k | tq(a0,p0) | vm(m1)
      if (sec == 0) out = kb[j];
      else if (sec == 1) {
        const float* R = a_rel + (size_t)h * 4096 + (size_t)rr * 64;
        float s = 0.f; for (int f = 0; f < 64; ++f) s += qb[h * 64 + f] * R[f];
        out = s * p_rel[h] * 0.125f;
      } else {
        const float* Mm = m_rel + RSZ + (size_t)h * 4096;
        float s = 0.f; for (int d = 0; d < 64; ++d) s += vb[h * 64 + d] * Mm[d * 64 + rr]; out = s;
      }
    } else if (gemm == 1) {  // C1: k | tq(a1,p1) | vm(m0)
      if (sec == 0) out = kb[D + j];
      else if (sec == 1) {
        const float* R = a_rel + RSZ + (size_t)h * 4096 + (size_t)rr * 64;
        float s = 0.f; for (int f = 0; f < 64; ++f) s += qb[D + h * 64 + f] * R[f];
        out = s * p_rel[H + h] * 0.125f;
      } else {
        const float* Mm = m_rel + (size_t)h * 4096;
        float s = 0.f; for (int d = 0; d < 64; ++d) s += vb[D + h * 64 + d] * Mm[d * 64 + rr]; out = s;
      }
    } else if (gemm == 2) {  // M2: tq(a2,p2)
      const float* R = a_rel + 2 * RSZ + (size_t)h * 4096 + (size_t)rr * 64;
      float s = 0.f; for (int f = 0; f < 64; ++f) s += qb[2 * D + h * 64 + f] * R[f];
      out = s * p_rel[2 * H + h] * 0.125f;
    } else {  // C2: k | vm(m2)
      if (sec == 0) out = kb[3 * D + j];
      else {
        const float* Mm = m_rel + 2 * RSZ + (size_t)h * 4096;
        float s = 0.f; for (int d = 0; d < 64; ++d) s += vb[3 * D + h * 64 + d] * Mm[d * 64 + rr]; out = s;
      }
    }
    bbuf[i] = out;
    return;
  }
  // ---- weight slots (R10 z-order) ----
  int z = q / 144;
  int r = q % 144;
  int px = r % 12, py = r / 12;
  int tx = t & 31, ty16 = t >> 5;  // ty16 in [0,16)
  const float* src; const float* rel = nullptr; const float* prl = nullptr; int type = 0;
  switch (z) {
    case 0: src = lin_W; break;
    case 1: src = lin_W + WSZ; break;
    case 2: src = kW; break;                                              // k_M1
    case 3: type = 1; src = qW; rel = a_rel; prl = p_rel; break;          // tq_M1
    case 4: type = 2; src = vW; rel = m_rel + RSZ; break;                 // vm_M1
    case 5: src = kW + WSZ; break;                                        // k_C1
    case 6: type = 1; src = qW + WSZ; rel = a_rel + RSZ; prl = p_rel + H; break;  // tq_C1
    case 7: type = 2; src = vW + WSZ; rel = m_rel; break;                 // vm_C1
    case 8: type = 1; src = qW + 2 * WSZ; rel = a_rel + 2 * RSZ; prl = p_rel + 2 * H; break;  // tq_M2
    case 9: src = kW + 3 * WSZ; break;                                    // k_C2
    case 10: type = 2; src = vW + 3 * WSZ; rel = m_rel + 2 * RSZ; break;  // vm_C2
    case 11: src = aW; break;
    case 12: src = aW + WSZ; break;
    default: src = aW + 2 * WSZ; break;
  }
  unsigned short* dst = wbuf + (size_t)z * WSZ;
  int bx = px * 32;  // k range
  int by = py * 32;  // n range
  if (type == 0) {
    float (*tile)[33] = (float(*)[33])smem;
#pragma unroll
    for (int s = 0; s < 2; ++s) {
      int r2 = ty16 + s * 16;
      tile[r2][tx] = src[(size_t)(bx + r2) * D + by + tx];
    }
    __syncthreads();
#pragma unroll
    for (int s = 0; s < 2; ++s) {
      int ny = ty16 + s * 16;
      dst[(size_t)(by + ny) * D + bx + tx] = f2bf(tile[tx][ny]);
    }
  } else if (type == 1) {
    float (*Wt_)[65] = (float(*)[65])smem;
    float (*Rt)[65] = (float(*)[65])(smem + 8320);
    int h = by >> 6, d0 = by & 63;
    float sc = prl[h] * 0.125f;
#pragma unroll
    for (int i = 0; i < 4; ++i) {
      int idx = t + i * 512;
      int wr = idx >> 6, wc = idx & 63;
      Wt_[wr][wc] = src[(size_t)(bx + wr) * D + h * 64 + wc];
      Rt[wr][wc] = rel[(size_t)h * 4096 + (size_t)(d0 + wr) * 64 + wc];
    }
    __syncthreads();
#pragma unroll
    for (int s = 0; s < 2; ++s) {
      int ny = ty16 + s * 16;
      float acc = 0.f;
#pragma unroll 16
      for (int f = 0; f < 64; ++f) acc += Wt_[tx][f] * Rt[ny][f];
      dst[(size_t)(by + ny) * D + bx + tx] = f2bf(acc * sc);
    }
  } else {
    float (*Wt2)[65] = (float(*)[65])smem;
    float (*Mt)[33] = (float(*)[33])(smem + 8320);
    int h = by >> 6, f0 = by & 63;
#pragma unroll
    for (int i = 0; i < 4; ++i) {
      int idx = t + i * 512;
      int wr = idx >> 6, wc = idx & 63;
      Wt2[wr][wc] = src[(size_t)(bx + wr) * D + h * 64 + wc];
      int dr = idx >> 5, fc = idx & 31;
      Mt[dr][fc] = rel[(size_t)h * 4096 + (size_t)dr * 64 + f0 + fc];
    }
    __syncthreads();
#pragma unroll
    for (int s = 0; s < 2; ++s) {
      int ny = ty16 + s * 16;
      float acc = 0.f;
#pragma unroll 16
      for (int d = 0; d < 64; ++d) acc += Wt2[tx][d] * Mt[d][ny];
      dst[(size_t)(by + ny) * D + bx + tx] = f2bf(acc);
    }
  }
}

// wave-shuffle scan: 3 barriers per 1024-chunk
__global__ void scan2_kernel(const int* __restrict__ deg0, int* __restrict__ off0, int N0,
                             const int* __restrict__ deg1, int* __restrict__ off1, int N1) {
  const int* deg = blockIdx.x ? deg1 : deg0;
  int* off = blockIdx.x ? off1 : off0;
  int N = blockIdx.x ? N1 : N0;
  __shared__ int wsum[16];
  __shared__ int carrySh;
  int tid = threadIdx.x;
  int lane = tid & 63, wid = tid >> 6;
  if (tid == 0) carrySh = 0;
  __syncthreads();
  for (int base = 0; base < N; base += 1024) {
    int i = base + tid;
    int v = (i < N) ? deg[i] : 0;
    int s = v;
#pragma unroll
    for (int o = 1; o < 64; o <<= 1) {
      int t2 = __shfl_up(s, o);
      if (lane >= o) s += t2;
    }
    if (lane == 63) wsum[wid] = s;
    __syncthreads();
    int wpre = 0;
    for (int j = 0; j < wid; ++j) wpre += wsum[j];
    int c = carrySh;
    if (i < N) off[i] = c + wpre + s - v;
    __syncthreads();
    if (tid == 1023) carrySh = c + wpre + s;
    __syncthreads();
  }
  if (tid == 0) off[N] = carrySh;
}

// ---------------- fused per-dst attention, u32-vectorized, 2-edge unrolled ----------------
struct AttnP {
  const unsigned short* kb;
  const unsigned short* tqb;
  const unsigned short* vmb;
  const int* off;
  const int* elist;
  unsigned short* aggb;
  int N, sk, st, sv, nb;
};

__global__ void attn_kernel(AttnP a0, AttnP a1) {
  bool first = (int)blockIdx.x < a0.nb;
  AttnP a = first ? a0 : a1;
  int bx = first ? (int)blockIdx.x : (int)blockIdx.x - a0.nb;
  int node = bx * 4 + (threadIdx.x >> 6);
  int lane = threadIdx.x & 63;
  if (node >= a.N) return;
  int e0 = a.off[node], e1 = a.off[node + 1];
  const uint_* tq32 = (const uint_*)(a.tqb + (size_t)node * a.st);
  float tq0[3], tq1[3], m[3], den[3], ac0[3], ac1[3];
#pragma unroll
  for (int j = 0; j < 3; ++j) {
    uint_ u = tq32[lane + 64 * j];
    tq0[j] = blo(u); tq1[j] = bhi(u);
    m[j] = -1e30f; den[j] = 0.f; ac0[j] = 0.f; ac1[j] = 0.f;
  }
  int i = e0;
  for (; i + 2 <= e1; i += 2) {
    int s0 = a.elist[i], s1 = a.elist[i + 1];
    const uint_* k0 = (const uint_*)(a.kb + (size_t)s0 * a.sk);
    const uint_* k1 = (const uint_*)(a.kb + (size_t)s1 * a.sk);
    const uint_* v0 = (const uint_*)(a.vmb + (size_t)s0 * a.sv);
    const uint_* v1 = (const uint_*)(a.vmb + (size_t)s1 * a.sv);
    float pa[3], pb[3]; uint_ va[3], vb[3];
#pragma unroll
    for (int j = 0; j < 3; ++j) {
      uint_ ka = k0[lane + 64 * j], kbu = k1[lane + 64 * j];
      va[j] = v0[lane + 64 * j]; vb[j] = v1[lane + 64 * j];
      pa[j] = blo(ka) * tq0[j] + bhi(ka) * tq1[j];
      pb[j] = blo(kbu) * tq0[j] + bhi(kbu) * tq1[j];
    }
#pragma unroll
    for (int o = 1; o <= 16; o <<= 1)
#pragma unroll
      for (int j = 0; j < 3; ++j) {
        pa[j] += __shfl_xor(pa[j], o);
        pb[j] += __shfl_xor(pb[j], o);
      }
#pragma unroll
    for (int j = 0; j < 3; ++j) {
      float mn = fmaxf(m[j], fmaxf(pa[j], pb[j]));
      float r = __expf(m[j] - mn);
      float p0 = __expf(pa[j] - mn);
      float p1 = __expf(pb[j] - mn);
      den[j] = den[j] * r + p0 + p1;
      ac0[j] = ac0[j] * r + p0 * blo(va[j]) + p1 * blo(vb[j]);
      ac1[j] = ac1[j] * r + p0 * bhi(va[j]) + p1 * bhi(vb[j]);
      m[j] = mn;
    }
  }
  if (i < e1) {
    int s0 = a.elist[i];
    const uint_* k0 = (const uint_*)(a.kb + (size_t)s0 * a.sk);
    const uint_* v0 = (const uint_*)(a.vmb + (size_t)s0 * a.sv);
    float pa[3]; uint_ va[3];
#pragma unroll
    for (int j = 0; j < 3; ++j) {
      uint_ ka = k0[lane + 64 * j];
      va[j] = v0[lane + 64 * j];
      pa[j] = blo(ka) * tq0[j] + bhi(ka) * tq1[j];
    }
#pragma unroll
    for (int o = 1; o <= 16; o <<= 1)
#pragma unroll
      for (int j = 0; j < 3; ++j) pa[j] += __shfl_xor(pa[j], o);
#pragma unroll
    for (int j = 0; j < 3; ++j) {
      float mn = fmaxf(m[j], pa[j]);
      float r = __expf(m[j] - mn);
      float p0 = __expf(pa[j] - mn);
      den[j] = den[j] * r + p0;
      ac0[j] = ac0[j] * r + p0 * blo(va[j]);
      ac1[j] = ac1[j] * r + p0 * bhi(va[j]);
      m[j] = mn;
    }
  }
  uint_* op32 = (uint_*)(a.aggb + (size_t)node * D);
#pragma unroll
  for (int j = 0; j < 3; ++j) {
    float o0 = (e1 > e0) ? ac0[j] / den[j] : 0.f;
    float o1 = (e1 > e0) ? ac1[j] / den[j] : 0.f;
    op32[lane + 64 * j] = (uint_)f2bf(geluf(o0)) | ((uint_)f2bf(geluf(o1)) << 16);
  }
}

// ---------------- MFMA bf16 GEMM, dual-problem, double-buffered; z==2 slice = scatter ----------------
struct GemmP {
  const unsigned short* A;
  const unsigned short* Wt;
  const float* bias;
  float* Cf;
  unsigned short* Cb;
  const unsigned short* xold;  // bf16 skip input
  const float* skipPtr;
  int M, N, cpitch, relu;
};
struct ScatP {
  const int *d0, *s0, *off0;
  int *cur0, *el0;
  const int *d1, *s1, *off1;
  int *cur1, *el1;
  int E;
};

__global__ __launch_bounds__(256) void gemm_bf16(GemmP q0, GemmP q1, ScatP sc) {
  if (blockIdx.z == 2) {
    int nb = gridDim.x * gridDim.y;
    int flat = blockIdx.y * gridDim.x + blockIdx.x;
    for (int e = flat * 256 + threadIdx.x; e < 2 * sc.E; e += nb * 256) {
      if (e < sc.E) {
        int d = sc.d0[e];
        sc.el0[sc.off0[d] + atomicAdd(&sc.cur0[d], 1)] = sc.s0[e];
      } else {
        int ee = e - sc.E;
        int d = sc.d1[ee];
        sc.el1[sc.off1[d] + atomicAdd(&sc.cur1[d], 1)] = sc.s1[ee];
      }
    }
    return;
  }
  GemmP p = blockIdx.z ? q1 : q0;
  const int bm = blockIdx.x * 128, bn = blockIdx.y * 128;
  if (bm >= p.M || bn >= p.N) return;
  __shared__ __align__(16) unsigned short As[2][128 * 64];
  __shared__ __align__(16) unsigned short Bs[2][128 * 64];
  const int tid = threadIdx.x;
  const int w = tid >> 6, lane = tid & 63;

  auto stage = [&](int t, int buf) {
#pragma unroll
    for (int i = 0; i < 4; ++i) {
      int cid = (w * 4 + i) * 64 + lane;
      int row = cid >> 3;
      int cg = (cid & 7) ^ (row & 7);
      int grow = bm + row;
      if (grow >= p.M) grow = p.M - 1;
      const unsigned short* gp = p.A + (size_t)grow * D + t * 64 + cg * 8;
      __builtin_amdgcn_global_load_lds((const __attribute__((address_space(1))) void*)gp,
                                       (__attribute__((address_space(3))) void*)&As[buf][(w * 4 + i) * 512],
                                       16, 0, 0);
    }
#pragma unroll
    for (int i = 0; i < 4; ++i) {
      int cid = (w * 4 + i) * 64 + lane;
      int row = cid >> 3;
      int cg = (cid & 7) ^ (row & 7);
      const unsigned short* gp = p.Wt + (size_t)(bn + row) * D + t * 64 + cg * 8;
      __builtin_amdgcn_global_load_lds((const __attribute__((address_space(1))) void*)gp,
                                       (__attribute__((address_space(3))) void*)&Bs[buf][(w * 4 + i) * 512],
                                       16, 0, 0);
    }
  };

  stage(0, 0);
  __syncthreads();

  const int wr = w >> 1, wc = w & 1;
  const int la = lane & 15, hi = lane >> 4;
  f32x4 acc[4][4] = {};

  for (int t = 0; t < 6; ++t) {
    if (t < 5) stage(t + 1, (t + 1) & 1);
    const unsigned short* Ab = As[t & 1];
    const unsigned short* Bb = Bs[t & 1];
#pragma unroll
    for (int ks = 0; ks < 2; ++ks) {
      int c = ks * 4 + hi;
      short8 af[4], bfr[4];
#pragma unroll
      for (int mi = 0; mi < 4; ++mi) {
        int row = wr * 64 + mi * 16 + la;
        af[mi] = *(const short8*)&Ab[row * 64 + ((c ^ (row & 7)) * 8)];
      }
#pragma unroll
      for (int n = 0; n < 4; ++n) {
        int col = wc * 64 + n * 16 + la;
        bfr[n] = *(const short8*)&Bb[col * 64 + ((c ^ (col & 7)) * 8)];
      }
#pragma unroll
      for (int mi = 0; mi < 4; ++mi)
#pragma unroll
        for (int n = 0; n < 4; ++n)
          acc[mi][n] = __builtin_amdgcn_mfma_f32_16x16x32_bf16(af[mi], bfr[n], acc[mi][n], 0, 0, 0);
    }
    __syncthreads();
  }

  float sa = 0.f;
  if (p.xold) sa = 1.0f / (1.0f + __expf(-*p.skipPtr));
#pragma unroll
  for (int mi = 0; mi < 4; ++mi) {
#pragma unroll
    for (int n = 0; n < 4; ++n) {
#pragma unroll
      for (int r = 0; r < 4; ++r) {
        int row = bm + wr * 64 + mi * 16 + hi * 4 + r;
        int col = bn + wc * 64 + n * 16 + la;
        if (row >= p.M) continue;
        float v = acc[mi][n][r] + p.bias[col];
        if (p.relu) v = fmaxf(v, 0.f);
        if (p.xold) v = sa * v + (1.0f - sa) * bf2f(p.xold[(size_t)row * D + col]);
        if (p.Cf) p.Cf[(size_t)row * p.cpitch + col] = v;
        if (p.Cb) p.Cb[(size_t)row * p.cpitch + col] = f2bf(v);
      }
    }
  }
}

extern "C" void kernel_launch(void* const* d_in, const int* in_sizes, int n_in,
                              void* d_out, int out_size, void* d_ws, size_t ws_size,
                              hipStream_t stream) {
  const float* tok_msg = (const float*)d_in[0];
  const float* tok_con = (const float*)d_in[1];
  const int* ids_msg = (const int*)d_in[2];
  const int* ids_con = (const int*)d_in[3];
  const int* src_cm = (const int*)d_in[4];
  const int* dst_cm = (const int*)d_in[5];
  const int* src_mc = (const int*)d_in[6];
  const int* dst_mc = (const int*)d_in[7];
  const float* lin_W = (const float*)d_in[8];
  const float* lin_b = (const float*)d_in[9];
  const float* kW = (const float*)d_in[10];
  const float* kb = (const float*)d_in[11];
  const float* qW = (const float*)d_in[12];
  const float* qb = (const float*)d_in[13];
  const float* vW = (const float*)d_in[14];
  const float* vb = (const float*)d_in[15];
  const float* aW = (const float*)d_in[16];
  const float* ab = (const float*)d_in[17];
  const float* a_rel = (const float*)d_in[18];
  const float* m_rel = (const float*)d_in[19];
  const float* p_rel = (const float*)d_in[20];
  const float* skip = (const float*)d_in[21];

  const int NM = in_sizes[2] / L;
  const int NC = in_sizes[3] / L;
  const int E = in_sizes[4];

  char* wsb = (char*)d_ws;
  size_t woff = 0;
  auto alloc = [&](size_t bytes) {
    woff = (woff + 255) & ~(size_t)255;
    void* p = wsb + woff;
    woff += bytes;
    return p;
  };
  const size_t NMe = (size_t)NM * D, NCe = (size_t)NC * D;
  unsigned short* poolM = (unsigned short*)alloc(NMe * 2);
  unsigned short* poolC = (unsigned short*)alloc(NCe * 2);
  unsigned short* x0b = (unsigned short*)alloc(NMe * 2);
  unsigned short* x1b = (unsigned short*)alloc(NCe * 2);
  unsigned short* xn0b = (unsigned short*)alloc(NMe * 2);
  unsigned short* xn1b = (unsigned short*)alloc(NCe * 2);
  unsigned short* projM1 = (unsigned short*)alloc((size_t)NM * 1152 * 2);
  unsigned short* projC1 = (unsigned short*)alloc((size_t)NC * 1152 * 2);
  unsigned short* projM2 = (unsigned short*)alloc((size_t)NM * 384 * 2);
  unsigned short* projC2 = (unsigned short*)alloc((size_t)NC * 768 * 2);
  unsigned short* aggM = (unsigned short*)alloc(NMe * 2);
  unsigned short* aggC = (unsigned short*)alloc(NCe * 2);
  unsigned short* wbuf = (unsigned short*)alloc(14 * WSZ * 2);
  float* bbuf = (float*)alloc(3456 * 4);
  // CSR ints: ONE contiguous block, hand-sliced (no per-array padding)
  long nz = 2L * NM + 2L * NC;  // deg0|cur0|deg1|cur1 prefix zeroed every launch
  int* ibase = (int*)alloc((size_t)(nz + NM + 1 + NC + 1 + 2L * E) * 4);
  int* deg0 = ibase;
  int* cur0 = deg0 + NM;
  int* deg1 = cur0 + NM;
  int* cur1 = deg1 + NC;
  int* off0 = cur1 + NC;
  int* off1 = off0 + NM + 1;
  int* el0 = off1 + NC + 1;
  int* el1 = el0 + E;

  dim3 b256(256);
  const int mbM = (NM + 127) / 128, mbC = (NC + 127) / 128;
  const int mbMax = (mbM > mbC) ? mbM : mbC;
  ScatP scNone = {};
  ScatP scAll = {dst_cm, src_cm, off0, cur0, el0, dst_mc, src_mc, off1, cur1, el1, E};

  // 1) zero deg/cur
  zero_int_kernel<<<64, b256, 0, stream>>>(ibase, nz);

  // 2) pool+count (HBM-bound) with weight/bias prep riding along (union LDS -> full occupancy)
  const int NPOOL = NM + NC;
  const int CH = (2 * E + NPOOL - 1) / NPOOL;
  poolprep_kernel<<<NPOOL + 14 * 144 + 7, 512, 0, stream>>>(
      tok_msg, ids_msg, poolM, NM, tok_con, ids_con, poolC, NPOOL,
      dst_cm, dst_mc, deg0, deg1, E, CH,
      lin_W, kW, qW, vW, aW, a_rel, m_rel, p_rel, kb, qb, vb, wbuf, bbuf);

  // 3) scan (tiny)
  scan2_kernel<<<2, 1024, 0, stream>>>(deg0, off0, NM, deg1, off1, NC);

  // 4) initial linear (relu) || CSR scatter (z==2)
  {
    GemmP p0 = {poolM, wbuf, lin_b, nullptr, x0b, nullptr, nullptr, NM, D, D, 1};
    GemmP p1 = {poolC, wbuf + WSZ, lin_b + D, nullptr, x1b, nullptr, nullptr, NC, D, D, 1};
    gemm_bf16<<<dim3(mbMax, 3, 3), b256, 0, stream>>>(p0, p1, scAll);
  }
  // 5) layer 1: fused k|tq|vm projections, both node types
  {
    GemmP p0 = {x0b, wbuf + 2 * WSZ, bbuf, nullptr, projM1, nullptr, nullptr, NM, 1152, 1152, 0};
    GemmP p1 = {x1b, wbuf + 5 * WSZ, bbuf + 1152, nullptr, projC1, nullptr, nullptr, NC, 1152, 1152, 0};
    gemm_bf16<<<dim3(mbMax, 9, 2), b256, 0, stream>>>(p0, p1, scNone);
  }
  // 6) layer 1 attention, both edge types
  {
    AttnP a0 = {projC1, projM1 + 384, projC1 + 768, off0, el0, aggM, NM, 1152, 1152, 1152, (NM + 3) / 4};
    AttnP a1 = {projM1, projC1 + 384, projM1 + 768, off1, el1, aggC, NC, 1152, 1152, 1152, (NC + 3) / 4};
    attn_kernel<<<(NM + 3) / 4 + (NC + 3) / 4, b256, 0, stream>>>(a0, a1);
  }
  // 7) layer 1 a-proj + skip blend (bf16 xold)
  {
    GemmP p0 = {aggM, wbuf + 11 * WSZ, ab, nullptr, xn0b, x0b, skip + 0, NM, D, D, 0};
    GemmP p1 = {aggC, wbuf + 12 * WSZ, ab + D, nullptr, xn1b, x1b, skip + 1, NC, D, D, 0};
    gemm_bf16<<<dim3(mbMax, 3, 2), b256, 0, stream>>>(p0, p1, scNone);
  }
  // 8) layer 2 projections (M: tq only, N=384; C: k|vm, N=768)
  {
    GemmP p0 = {xn0b, wbuf + 8 * WSZ, bbuf + 2304, nullptr, projM2, nullptr, nullptr, NM, 384, 384, 0};
    GemmP p1 = {xn1b, wbuf + 9 * WSZ, bbuf + 2688, nullptr, projC2, nullptr, nullptr, NC, 768, 768, 0};
    gemm_bf16<<<dim3(mbMax, 6, 2), b256, 0, stream>>>(p0, p1, scNone);
  }
  // 9) layer 2 attention (edge type 0 only)
  {
    AttnP a0 = {projC2, projM2, projC2 + 384, off0, el0, aggM, NM, 768, 384, 768, (NM + 3) / 4};
    AttnP a1 = a0;
    attn_kernel<<<(NM + 3) / 4, b256, 0, stream>>>(a0, a1);
  }
  // 10) layer 2 a-proj -> d_out (f32), bf16 xold
  {
    GemmP p0 = {aggM, wbuf + 13 * WSZ, ab + 2 * D, (float*)d_out, nullptr, xn0b, skip + 2, NM, D, D, 0};
    GemmP p1 = p0;
    gemm_bf16<<<dim3(mbM, 3, 1), b256, 0, stream>>>(p0, p1, scNone);
  }
}